// Round 1
// baseline (489.443 us; speedup 1.0000x reference)
//
#include <hip/hip_runtime.h>

typedef short short8  __attribute__((ext_vector_type(8)));
typedef short short4v __attribute__((ext_vector_type(4)));
typedef float f32x4   __attribute__((ext_vector_type(4)));

#define MFMA_BF16(A,B,C) __builtin_amdgcn_mfma_f32_16x16x32_bf16((A),(B),(C),0,0,0)

__device__ __forceinline__ short bf16bits(float f){
  return (short)__builtin_bit_cast(unsigned short, static_cast<__bf16>(f));
}

// ---------------- mask preprocessing ----------------
// region_masks: [R=2][T=121][MH=88][MW=160] (B=1). Latent grid 16x44x80.
// Trilinear (half-pixel): t=0 -> frame 0; t>=1 -> avg frames (8t-4, 8t-3).
// H,W downsample by 2 -> 2x2 average. allowed bits: b0=global, b1=region0, b2=region1.
__global__ __launch_bounds__(256) void maskprep_kernel(const float* __restrict__ rm,
                                                       unsigned* __restrict__ allowed){
  int s = blockIdx.x*256 + threadIdx.x;
  if (s >= 56320) return;
  int t = s / 3520;
  int rem = s - t*3520;
  int i = rem / 80;
  int j = rem - i*80;
  int y = 2*i, x = 2*j;
  bool bin[2];
  #pragma unroll
  for (int r=0;r<2;r++){
    const float* base = rm + (size_t)r*121*88*160;
    float acc;
    if (t == 0){
      const float* p0 = base + (size_t)(0*88 + y)*160 + x;
      acc = 0.25f*(p0[0]+p0[1]+p0[160]+p0[161]);
    } else {
      const float* pa = base + (size_t)((8*t-4)*88 + y)*160 + x;
      const float* pb = base + (size_t)((8*t-3)*88 + y)*160 + x;
      acc = 0.125f*(pa[0]+pa[1]+pa[160]+pa[161] + pb[0]+pb[1]+pb[160]+pb[161]);
    }
    bin[r] = acc > 0.5f;
  }
  unsigned bits = (bin[0]||bin[1]) ? 0u : 1u;
  if (bin[0]) bits |= 2u;
  if (bin[1]) bits |= 4u;
  allowed[s] = bits;
}

// ---------------- K/V preprocessing ----------------
// Build Kb[h][seg][p][d] (bf16) and VT[h][d][seg*128+p] (bf16) from fp32 inputs.
// k,v: [1,128,8,64]; rk,rv: [2,1,128,8,64].
__global__ __launch_bounds__(256) void kvprep_kernel(const float* __restrict__ k,
                                                     const float* __restrict__ v,
                                                     const float* __restrict__ rk,
                                                     const float* __restrict__ rv,
                                                     unsigned short* __restrict__ Kb,
                                                     unsigned short* __restrict__ VT){
  int idx = blockIdx.x*256 + threadIdx.x;   // over 3*128*8*64 = 196608
  if (idx >= 3*128*8*64) return;
  int d   = idx & 63;
  int h   = (idx >> 6) & 7;
  int p   = (idx >> 9) & 127;
  int seg = idx >> 16;
  int low = idx & 65535;                    // (p*8+h)*64+d
  float kv_, vv_;
  if (seg == 0){ kv_ = k[low];                     vv_ = v[low]; }
  else         { kv_ = rk[(size_t)(seg-1)*65536 + low]; vv_ = rv[(size_t)(seg-1)*65536 + low]; }
  Kb[((h*3 + seg)*128 + p)*64 + d]    = (unsigned short)bf16bits(kv_);
  VT[(h*64 + d)*384 + seg*128 + p]    = (unsigned short)bf16bits(vv_);
}

// ---------------- fused regional+base attention ----------------
// Transposed compute: S^T = K·Q^T (M=keys, N=queries). C-layout: lane holds
// query col = lane&15 (ONE query per lane -> scalar masking, xor16/32 softmax
// reduce), key rows = quad*4+reg (+16*tile). Merged coeff = 0.5*p_reg +
// (key<128)*0.5*p_base -> bf16 -> LDS P^T -> out^T = V^T·P^T (one PV pass).
__global__ __launch_bounds__(256) void attn_kernel(const float* __restrict__ q,
                                                   const unsigned* __restrict__ allowed,
                                                   const unsigned short* __restrict__ Kb,
                                                   const unsigned short* __restrict__ VT,
                                                   float* __restrict__ out){
  constexpr int H = 8, D = 64;
  const int h    = blockIdx.y;
  const int wave = threadIdx.x >> 6;
  const int lane = threadIdx.x & 63;
  const int c    = lane & 15;        // query col (also d_local / key_local for A-frags)
  const int Q    = lane >> 4;        // quad
  const int s0   = blockIdx.x*64 + wave*16;
  const int s    = s0 + c;

  // per-wave P^T buffer: [16 queries][392 shorts] (384 keys + pad), 16B-aligned rows
  __shared__ __align__(16) unsigned short pt[4*16*392];
  unsigned short* myrow = pt + wave*(16*392) + c*392;

  // ---- Q fragments (B-operand of S^T): B[kdim=d][n=query], lane: d = Q*8+j (+32f)
  const float* qp = q + ((size_t)s*H + h)*D + Q*8;
  f32x4 qa = *(const f32x4*)(qp);
  f32x4 qb = *(const f32x4*)(qp + 4);
  f32x4 qc_ = *(const f32x4*)(qp + 32);
  f32x4 qd = *(const f32x4*)(qp + 36);
  short8 qf0, qf1;
  #pragma unroll
  for (int jj=0;jj<4;jj++){
    qf0[jj]   = bf16bits(qa[jj]);
    qf0[4+jj] = bf16bits(qb[jj]);
    qf1[jj]   = bf16bits(qc_[jj]);
    qf1[4+jj] = bf16bits(qd[jj]);
  }

  // ---- scores: 24 key-tiles of 16; A = K-frag (key=c, d=Q*8+j+32f)
  const unsigned short* kbase = Kb + (size_t)h*3*128*64;
  float sc[24][4];
  #pragma unroll
  for (int t=0;t<24;t++){
    const unsigned short* kp = kbase + (t*16 + c)*64 + Q*8;
    short8 kf0 = *(const short8*)(kp);
    short8 kf1 = *(const short8*)(kp + 32);
    f32x4 acc = {0.f,0.f,0.f,0.f};
    acc = MFMA_BF16(kf0, qf0, acc);
    acc = MFMA_BF16(kf1, qf1, acc);
    #pragma unroll
    for (int r=0;r<4;r++) sc[t][r] = acc[r]*0.125f;   // D^-0.5
  }

  // ---- softmax stats (per query = per lane&15 group)
  const unsigned ab = allowed[s];
  float mreg = -3.0e38f, mbase = -3.0e38f;
  #pragma unroll
  for (int t=0;t<24;t++){
    const bool al = (ab >> (t>>3)) & 1u;
    #pragma unroll
    for (int r=0;r<4;r++){
      float v0 = sc[t][r];
      mreg = fmaxf(mreg, al ? v0 : -3.0e38f);
      if (t < 8) mbase = fmaxf(mbase, v0);
    }
  }
  mreg  = fmaxf(mreg,  __shfl_xor(mreg, 16));
  mreg  = fmaxf(mreg,  __shfl_xor(mreg, 32));
  mbase = fmaxf(mbase, __shfl_xor(mbase, 16));
  mbase = fmaxf(mbase, __shfl_xor(mbase, 32));

  float lreg = 0.f, lbase = 0.f;
  #pragma unroll
  for (int t=0;t<24;t++){
    const bool al = (ab >> (t>>3)) & 1u;
    #pragma unroll
    for (int r=0;r<4;r++){
      float v0 = sc[t][r];
      float e  = al ? __expf(v0 - mreg) : 0.f;
      lreg += e;
      if (t < 8) lbase += __expf(v0 - mbase);   // keep raw scores for t<8
      else       sc[t][r] = e;                  // t>=8: store regional exp in place
    }
  }
  lreg  += __shfl_xor(lreg, 16);  lreg  += __shfl_xor(lreg, 32);
  lbase += __shfl_xor(lbase, 16); lbase += __shfl_xor(lbase, 32);
  const float invr = 0.5f/lreg, invb = 0.5f/lbase;

  // ---- merged coefficients -> bf16 -> LDS P^T[query][key]
  #pragma unroll
  for (int t=0;t<24;t++){
    short4v pk;
    if (t < 8){
      const bool al = (ab >> (t>>3)) & 1u;
      #pragma unroll
      for (int r=0;r<4;r++){
        float v0 = sc[t][r];
        float pp = (al ? __expf(v0 - mreg) : 0.f)*invr + __expf(v0 - mbase)*invb;
        pk[r] = bf16bits(pp);
      }
    } else {
      #pragma unroll
      for (int r=0;r<4;r++) pk[r] = bf16bits(sc[t][r]*invr);
    }
    *(short4v*)(myrow + t*16 + Q*4) = pk;       // keys t*16+Q*4..+3 of query c
  }
  __syncthreads();   // drain LDS writes before frag reads

  // ---- out^T = V^T · P^T : A = V^T-frag (d=m*16+c, key=kc*32+Q*8+j), B = P^T-frag
  f32x4 acc[4];
  #pragma unroll
  for (int m=0;m<4;m++) acc[m] = (f32x4){0.f,0.f,0.f,0.f};
  const unsigned short* vb = VT + (size_t)h*64*384;
  #pragma unroll
  for (int kc=0;kc<12;kc++){
    short8 pf = *(const short8*)(myrow + kc*32 + Q*8);
    #pragma unroll
    for (int m=0;m<4;m++){
      short8 vf = *(const short8*)(vb + (m*16 + c)*384 + kc*32 + Q*8);
      acc[m] = MFMA_BF16(vf, pf, acc[m]);
    }
  }

  // ---- store: lane holds d = m*16 + Q*4 + r for query s (fp32, 16B stores)
  float* ob = out + (size_t)s*512 + h*64 + Q*4;
  #pragma unroll
  for (int m=0;m<4;m++) *(f32x4*)(ob + m*16) = acc[m];
}

extern "C" void kernel_launch(void* const* d_in, const int* in_sizes, int n_in,
                              void* d_out, int out_size, void* d_ws, size_t ws_size,
                              hipStream_t stream) {
  const float* q  = (const float*)d_in[0];
  const float* k  = (const float*)d_in[1];
  const float* v  = (const float*)d_in[2];
  const float* rk = (const float*)d_in[3];
  const float* rv = (const float*)d_in[4];
  const float* rm = (const float*)d_in[5];
  float* out = (float*)d_out;

  char* ws = (char*)d_ws;
  unsigned*       allowed = (unsigned*)ws;                        // 56320*4   = 225280 B
  unsigned short* Kb      = (unsigned short*)(ws + 225280);       // 8*3*128*64*2 = 393216 B
  unsigned short* VT      = (unsigned short*)(ws + 225280 + 393216); // 393216 B

  maskprep_kernel<<<220, 256, 0, stream>>>(rm, allowed);
  kvprep_kernel<<<768, 256, 0, stream>>>(k, v, rk, rv, Kb, VT);
  dim3 grid(880, 8);
  attn_kernel<<<grid, 256, 0, stream>>>(q, allowed, Kb, VT, out);
}